// Round 3
// baseline (2351.179 us; speedup 1.0000x reference)
//
#include <hip/hip_runtime.h>
#include <hip/hip_bf16.h>
#include <stdint.h>

// Problem constants
#define T_STEPS 256
#define B_SZ    4096
#define I_SZ    144
#define H_SZ    32
#define W_LD    176   // H + I

// photonic sigmoid constants
#define PS_A1   0.06f
#define PS_A2   1.005f
#define PS_X0   0.145f
#define PS_CUT  2.0f

typedef const __attribute__((address_space(1))) void* gptr_t;
typedef __attribute__((address_space(3))) void* lptr_t;

// -----------------------------------------------------------------------------
// Kernel 1: U[row][j] = sum_i x[row][i] * Wx[j][i] + b[j]
// Wave-private double-buffered pipeline, NO barriers:
//   - LDS tile layout transposed by float4: buf[q][row] -> compute read
//     buf[q*64+lane] is lane-stride 16B = conflict-free ds_read_b128.
//   - global_load_lds: LDS dest contiguous (constraint), global side is a
//     per-lane row gather (lane*576B + q*16B); adjacent q instrs cover the
//     same 64B lines -> L2 merges -> 1x HBM fetch.
//   - half-tile phases (18 q's, 18KB): compute phase p overlaps the 18
//     in-flight loads of phase p+1 via exact s_waitcnt vmcnt(N).
//   - W reads wave-uniform -> s_load (round-1 codegen, VGPR=36).
// -----------------------------------------------------------------------------
__global__ __launch_bounds__(256) void gemm_u(
    const float* __restrict__ x,     // [ntiles*64][144] (chunk base)
    const float* __restrict__ W,     // [32][176], Wx = cols 32..175
    const float* __restrict__ bias,  // [32]
    float* __restrict__ U,           // [ntiles*64][32]
    int ntiles)
{
    // two DISTINCT shared objects (better alias analysis than one array)
    __shared__ __align__(16) float4 bufA[4][18 * 64];   // 73728 B
    __shared__ __align__(16) float4 bufB[4][18 * 64];   // 73728 B  (total 144 KB)

    const int lane = threadIdx.x & 63;
    const int wv   = threadIdx.x >> 6;
    float4* __restrict__ bA = bufA[wv];
    float4* __restrict__ bB = bufB[wv];

    const int wave_id = blockIdx.x * 4 + wv;
    const int nwaves  = gridDim.x * 4;
    const int tpw     = (ntiles + nwaves - 1) / nwaves;
    const int t0      = wave_id * tpw;
    const int t1      = (t0 + tpw < ntiles) ? (t0 + tpw) : ntiles;
    if (t0 >= t1) return;

    // issue one half-tile (18 q's) of tile t into buf
    auto issue = [&](int t, int qbase, float4* __restrict__ buf) {
        const float* g = x + (size_t)t * 64 * I_SZ + (size_t)lane * I_SZ + 4 * qbase;
#pragma unroll
        for (int q = 0; q < 18; ++q) {
            __builtin_amdgcn_global_load_lds((gptr_t)(g + 4 * q),
                                             (lptr_t)(buf + q * 64), 16, 0, 0);
        }
    };
    // compute one half-tile into acc
    auto compute = [&](const float4* __restrict__ buf, int qbase, float* acc) {
#pragma unroll
        for (int q = 0; q < 18; ++q) {
            float4 xv = buf[q * 64 + lane];
            const float* wp = W + H_SZ + 4 * (qbase + q);
#pragma unroll
            for (int j = 0; j < H_SZ; ++j) {
                float4 wv4 = *(const float4*)(wp + j * W_LD);   // uniform -> s_load
                acc[j] = fmaf(xv.x, wv4.x,
                         fmaf(xv.y, wv4.y,
                         fmaf(xv.z, wv4.z,
                         fmaf(xv.w, wv4.w, acc[j]))));
            }
        }
    };
    auto store = [&](int t, const float* acc) {
        float* ur = U + ((size_t)t * 64 + lane) * H_SZ;
#pragma unroll
        for (int k = 0; k < H_SZ; k += 4)
            *(float4*)(ur + k) = make_float4(acc[k], acc[k+1], acc[k+2], acc[k+3]);
    };

    float acc[H_SZ];

    // ---- prologue: fill both buffers for tile t0 ----
    issue(t0, 0,  bA);    // 18 in flight
    issue(t0, 18, bB);    // 36 in flight

    // ---- peeled first tile (exact counts: no stores outstanding yet) ----
    {
        int tn = (t0 + 1 < t1) ? t0 + 1 : t1 - 1;
#pragma unroll
        for (int j = 0; j < H_SZ; ++j) acc[j] = bias[j];
        asm volatile("s_waitcnt vmcnt(18)" ::: "memory");   // A(t0) done
        compute(bA, 0, acc);
        issue(tn, 0, bA);
        asm volatile("s_waitcnt vmcnt(18)" ::: "memory");   // B(t0) done
        compute(bB, 18, acc);
        issue(tn, 18, bB);
        store(t0, acc);
    }

    // ---- steady state: outstanding = [A(t) 18, B(t) 18, st(t-1) 8] ----
    for (int t = t0 + 1; t < t1; ++t) {
        int tn = (t + 1 < t1) ? t + 1 : t1 - 1;
#pragma unroll
        for (int j = 0; j < H_SZ; ++j) acc[j] = bias[j];
        asm volatile("s_waitcnt vmcnt(26)" ::: "memory");   // oldest 18 = A(t) done
        compute(bA, 0, acc);
        issue(tn, 0, bA);
        asm volatile("s_waitcnt vmcnt(26)" ::: "memory");   // oldest = B(t) done
        compute(bB, 18, acc);
        issue(tn, 18, bB);
        store(t, acc);
    }
}

// -----------------------------------------------------------------------------
// Kernel 2: recurrence  h = ps(h @ Wh.T + U[t])
// Block = 256 threads = 4 waves = 8 batches. lane j = tid&31 holds h_j.
// h broadcast via __shfl width-32 (no LDS, no barriers). 4 split FMA chains.
// U prefetched 8 steps deep in registers (superstep ~1200cyc > 900cyc HBM).
// -----------------------------------------------------------------------------
__global__ __launch_bounds__(256) void recur(
    const float* __restrict__ U,     // [Tc][B][32]
    const float* __restrict__ W,     // [32][176], Wh = cols 0..31
    float* __restrict__ hout,        // [B][32] running h state / final output
    int Tc, int first)
{
    const int tid = threadIdx.x;
    const int j   = tid & 31;
    const int b   = blockIdx.x * 8 + (tid >> 5);

    // Wh row j -> 32 registers
    float wh[H_SZ];
#pragma unroll
    for (int k = 0; k < H_SZ; k += 4) {
        float4 wv = *(const float4*)(W + j * W_LD + k);
        wh[k] = wv.x; wh[k+1] = wv.y; wh[k+2] = wv.z; wh[k+3] = wv.w;
    }

    float h;
    if (first) h = 0.0f;
    else       h = hout[(size_t)b * H_SZ + j];

    const float*  Up     = U + (size_t)b * H_SZ + j;
    const size_t  stride = (size_t)B_SZ * H_SZ;

    const float expC = (float)(1.0 / (0.033 * 0.6931471805599453)); // 1/(D*ln2)

    // depth-8 register prefetch pipeline
    float un[8];
#pragma unroll
    for (int i = 0; i < 8; ++i) {
        int tn = (i < Tc) ? i : (Tc - 1);
        un[i] = Up[(size_t)tn * stride];
    }

    for (int t0 = 0; t0 < Tc; t0 += 8) {
        float cur[8];
#pragma unroll
        for (int i = 0; i < 8; ++i) cur[i] = un[i];
        // issue next superstep's loads now; consumed 8 steps later
#pragma unroll
        for (int i = 0; i < 8; ++i) {
            int tn = t0 + 8 + i;
            if (tn >= Tc) tn = Tc - 1;
            un[i] = Up[(size_t)tn * stride];
        }
#pragma unroll
        for (int i = 0; i < 8; ++i) {
            if (t0 + i < Tc) {
                float hb = h;
                float s0 = cur[i], s1 = 0.0f, s2 = 0.0f, s3 = 0.0f;
#pragma unroll
                for (int k = 0; k < H_SZ; k += 4) {
                    s0 = fmaf(wh[k+0], __shfl(hb, k+0, 32), s0);
                    s1 = fmaf(wh[k+1], __shfl(hb, k+1, 32), s1);
                    s2 = fmaf(wh[k+2], __shfl(hb, k+2, 32), s2);
                    s3 = fmaf(wh[k+3], __shfl(hb, k+3, 32), s3);
                }
                float z  = (s0 + s1) + (s2 + s3);
                float zz = fminf(z - PS_X0, PS_CUT);
                float e  = exp2f(zz * expC);
                h = PS_A2 + (PS_A1 - PS_A2) / (1.0f + e);
            }
        }
    }

    hout[(size_t)b * H_SZ + j] = h;
}

// -----------------------------------------------------------------------------
extern "C" void kernel_launch(void* const* d_in, const int* in_sizes, int n_in,
                              void* d_out, int out_size, void* d_ws, size_t ws_size,
                              hipStream_t stream)
{
    const float* x    = (const float*)d_in[0];  // [256][4096][144]
    const float* W    = (const float*)d_in[1];  // [32][176]
    const float* bias = (const float*)d_in[2];  // [32]
    float* out = (float*)d_out;                 // [4096][32]
    float* U   = (float*)d_ws;

    // choose T-chunk that fits in workspace
    int Tc = T_STEPS;
    while ((size_t)Tc * B_SZ * H_SZ * sizeof(float) > ws_size && Tc > 1) Tc >>= 1;

    for (int t0 = 0; t0 < T_STEPS; t0 += Tc) {
        int tc = (t0 + Tc <= T_STEPS) ? Tc : (T_STEPS - t0);
        int nrows = tc * B_SZ;                 // multiple of 64
        gemm_u<<<256, 256, 0, stream>>>(
            x + (size_t)t0 * B_SZ * I_SZ, W, bias, U, nrows / 64);
        recur<<<B_SZ / 8, 256, 0, stream>>>(U, W, out, tc, t0 == 0 ? 1 : 0);
    }
}